// Round 19
// baseline (146.804 us; speedup 1.0000x reference)
//
#include <hip/hip_runtime.h>
#include <hip/hip_bf16.h>
#include <stdint.h>

#define B_ROWS 2048
#define SEQ 512
#define VOC 30000
#define DMODEL 768
#define K1 1.2f
#define BPAR 0.75f
#define NT 192    // gather: 3 waves; each thread owns one ushort4 (4 bf16) chunk
#define PF 8      // prefetch depth — proven operating point (6x)
#define NPART 8   // vocab partitions == XCD count; slice = 3750 tokens = 5.75 MB bf16
#define PSIZE (VOC / NPART)   // 3750
#define TGX 235   // ceil(VOC/128) transpose tiles in t
#define TGY 12    // DMODEL/64 transpose tiles in j
#define TTILES (TGX * TGY)           // 2820
#define NBLK (TTILES + B_ROWS)       // 4868

// ---------------- Kernel 1: fused W-transpose + doc-prep (interleaved, R18) ------------
// Added: after the sort, record 9 partition offsets per doc (poff[q] = first index with
// token >= q*PSIZE) so the gather can be sliced by vocab partition.
__launch_bounds__(256)
__global__ void prep_trans(const float* __restrict__ W, __hip_bfloat16* __restrict__ Wb,
                           const int* __restrict__ ids, const int* __restrict__ mask,
                           int* __restrict__ stoks_g, float* __restrict__ wts_g,
                           int* __restrict__ poff_g) {
    __shared__ ushort smem[64 * 130];   // 16,640 B
    __shared__ int poff[NPART + 1];
    uint32_t bid = blockIdx.x;
    int tid = threadIdx.x;

    uint32_t a  = bid * (uint32_t)B_ROWS / (uint32_t)NBLK;
    uint32_t b2 = (bid + 1u) * (uint32_t)B_ROWS / (uint32_t)NBLK;

    if (b2 == a) {
        // ---- transpose role (index = bid - a) ----
        ushort (*tile)[130] = (ushort(*)[130])smem;
        int tb = (int)(bid - a);
        int bx = tb % TGX, by = tb / TGX;
        int tBase = bx * 128;
        int jBase = by * 64;
        int tx = tid & 63;
        int ty = tid >> 6;

#pragma unroll
        for (int jj = 0; jj < 16; jj++) {
            int j = jBase + jj * 4 + ty;
            int t = tBase + tx * 2;
            if (t < VOC) {
                float2 v = *(const float2*)(W + (size_t)j * VOC + t);
                ushort2 u;
                u.x = __bfloat16_as_ushort(__float2bfloat16(v.x));
                u.y = __bfloat16_as_ushort(__float2bfloat16(v.y));
                *(ushort2*)&tile[jj * 4 + ty][tx * 2] = u;
            }
        }
        __syncthreads();

#pragma unroll
        for (int i = 0; i < 32; i++) {
            int trow = i * 4 + ty;
            int t = tBase + trow;
            if (t < VOC) {
                ((ushort*)Wb)[(size_t)t * DMODEL + jBase + tx] = tile[tx][trow];
            }
        }
    } else {
        // ---- doc-prep role (index = a) ----
        int b = (int)a;
        int*   stoks = (int*)smem;                    // 512 ints
        float* wts   = (float*)((char*)smem + 2048);  // 512 f32
        int*   nvp   = (int*)((char*)smem + 4096);

        if (tid == 0) *nvp = 0;
        __syncthreads();

        for (int i = tid; i < SEQ; i += 256) {
            int id = ids[(size_t)b * SEQ + i];
            int m  = mask[(size_t)b * SEQ + i];
            if (m == 1 && id > 100 && id < VOC) {
                stoks[atomicAdd(nvp, 1)] = id;
            }
        }
        __syncthreads();
        int n = *nvp;

        for (int i = n + tid; i < SEQ; i += 256) stoks[i] = 0x7fffffff;

        for (int k = 2; k <= SEQ; k <<= 1) {
            for (int j = k >> 1; j > 0; j >>= 1) {
                __syncthreads();
                for (int i = tid; i < SEQ; i += 256) {
                    int ixj = i ^ j;
                    if (ixj > i) {
                        int va = stoks[i], vc = stoks[ixj];
                        if ((va > vc) == ((i & k) == 0)) { stoks[i] = vc; stoks[ixj] = va; }
                    }
                }
            }
        }
        __syncthreads();

        float kln = K1 * fmaxf(1.0f + BPAR * ((float)n / 100.0f - 1.0f), 0.5f);
        for (int i = tid; i < n; i += 256) {
            int t = stoks[i];
            int lo = i; while (lo > 0 && stoks[lo - 1] == t) lo--;
            int hi = i; while (hi < n - 1 && stoks[hi + 1] == t) hi++;
            wts[i] = (K1 + 1.0f) / ((float)(hi - lo + 1) + kln);
        }

        // partition offsets: poff[q] = first i with stoks[i] >= q*PSIZE (defaults: 0 / n)
        if (tid <= NPART) poff[tid] = (tid == 0) ? 0 : n;
        __syncthreads();
        for (int i = tid; i < n; i += 256) {
            int cp = stoks[i] / PSIZE;
            int pp = (i == 0) ? -1 : stoks[i - 1] / PSIZE;
            for (int q = pp + 1; q <= cp; q++) if (q > 0) poff[q] = i;  // unique writer
        }
        __syncthreads();

        for (int i = tid; i < n; i += 256) {
            stoks_g[(size_t)b * SEQ + i] = stoks[i] * (DMODEL / 4);  // ushort4-row offset
            wts_g[(size_t)b * SEQ + i]   = wts[i];
        }
        if (tid <= NPART) poff_g[b * (NPART + 1) + tid] = poff[tid];
    }
}

__device__ __forceinline__ float b2f(unsigned short h) {
    union { uint32_t u; float f; } v; v.u = ((uint32_t)h) << 16; return v.f;
}

// ---------------- Kernel 2: partitioned gather (partial accumulate) --------------------
// part = bid & 7 -> XCD (round-robin dispatch), doc = bid >> 3. Each XCD touches only
// its 5.75 MB vocab slice of Wb -> L2-resident by construction (no reliance on emergent
// phase-lock). Inner PF=8 loop body VERBATIM from the 6x-proven gather; only the token
// list is the pre-sliced sub-range [poff[part], poff[part+1]).
__launch_bounds__(NT, 6)
__global__ void bm25_part(const int* __restrict__ stoks_g, const float* __restrict__ wts_g,
                          const int* __restrict__ poff_g,
                          const __hip_bfloat16* __restrict__ Wb,
                          __hip_bfloat16* __restrict__ part_g) {
    __shared__ int   stoks[SEQ];
    __shared__ float wts[SEQ];

    int part = blockIdx.x & (NPART - 1);
    int doc  = blockIdx.x >> 3;
    int tid = threadIdx.x;

    int lo = poff_g[doc * (NPART + 1) + part];
    int hi = poff_g[doc * (NPART + 1) + part + 1];
    int m = hi - lo;

    for (int i = tid; i < m; i += NT) {
        stoks[i] = stoks_g[(size_t)doc * SEQ + lo + i];
        wts[i]   = wts_g[(size_t)doc * SEQ + lo + i];
    }
    __syncthreads();

    const ushort4* __restrict__ Wb4 = (const ushort4*)Wb;
    float4 acc = make_float4(0.f, 0.f, 0.f, 0.f);
    int p = 0;
    for (; p + PF <= m; p += PF) {
        ushort4 r[PF];
        float   w[PF];
#pragma unroll
        for (int q = 0; q < PF; q++) {
            r[q] = Wb4[(size_t)stoks[p + q] + tid];
            w[q] = wts[p + q];
        }
#pragma unroll
        for (int q = 0; q < PF; q++) {
            acc.x = fmaf(w[q], b2f(r[q].x), acc.x);
            acc.y = fmaf(w[q], b2f(r[q].y), acc.y);
            acc.z = fmaf(w[q], b2f(r[q].z), acc.z);
            acc.w = fmaf(w[q], b2f(r[q].w), acc.w);
        }
    }
    for (; p < m; p++) {
        float w = wts[p];
        ushort4 r = Wb4[(size_t)stoks[p] + tid];
        acc.x = fmaf(w, b2f(r.x), acc.x);
        acc.y = fmaf(w, b2f(r.y), acc.y);
        acc.z = fmaf(w, b2f(r.z), acc.z);
        acc.w = fmaf(w, b2f(r.w), acc.w);
    }

    // bf16 partial (keeps ws <= 80 MB; adds ~1.4e-4 abs err, 3.7x margin remains)
    ushort4 o;
    o.x = __bfloat16_as_ushort(__float2bfloat16(acc.x));
    o.y = __bfloat16_as_ushort(__float2bfloat16(acc.y));
    o.z = __bfloat16_as_ushort(__float2bfloat16(acc.z));
    o.w = __bfloat16_as_ushort(__float2bfloat16(acc.w));
    ((ushort4*)part_g)[((size_t)doc * NPART + part) * NT + tid] = o;
}

// ---------------- Kernel 3: combine 8 partials + normalize -----------------------------
__launch_bounds__(NT)
__global__ void bm25_combine(const __hip_bfloat16* __restrict__ part_g,
                             float* __restrict__ out) {
    __shared__ float wred[3];
    int doc = blockIdx.x;
    int tid = threadIdx.x;

    float4 acc = make_float4(0.f, 0.f, 0.f, 0.f);
#pragma unroll
    for (int p = 0; p < NPART; p++) {
        ushort4 r = ((const ushort4*)part_g)[((size_t)doc * NPART + p) * NT + tid];
        acc.x += b2f(r.x);
        acc.y += b2f(r.y);
        acc.z += b2f(r.z);
        acc.w += b2f(r.w);
    }

    float ss = acc.x * acc.x + acc.y * acc.y + acc.z * acc.z + acc.w * acc.w;
#pragma unroll
    for (int off = 32; off > 0; off >>= 1) ss += __shfl_down(ss, off);
    if ((tid & 63) == 0) wred[tid >> 6] = ss;
    __syncthreads();
    float inv = rsqrtf(fmaxf(wred[0] + wred[1] + wred[2], 1e-30f));

    float4 o;
    o.x = acc.x * inv; o.y = acc.y * inv; o.z = acc.z * inv; o.w = acc.w * inv;
    ((float4*)(out + (size_t)doc * DMODEL))[tid] = o;
}

extern "C" void kernel_launch(void* const* d_in, const int* in_sizes, int n_in,
                              void* d_out, int out_size, void* d_ws, size_t ws_size,
                              hipStream_t stream) {
    const int*   ids  = (const int*)d_in[0];
    const int*   mask = (const int*)d_in[1];
    const float* W    = (const float*)d_in[2];
    float* out = (float*)d_out;

    char* ws = (char*)d_ws;
    __hip_bfloat16* Wb = (__hip_bfloat16*)ws;               // 46,080,000 B
    size_t off = (size_t)VOC * DMODEL * sizeof(__hip_bfloat16);
    int*   stoks_g = (int*)(ws + off);        off += (size_t)B_ROWS * SEQ * 4;   // 4 MB
    float* wts_g   = (float*)(ws + off);      off += (size_t)B_ROWS * SEQ * 4;   // 4 MB
    int*   poff_g  = (int*)(ws + off);        off += (size_t)B_ROWS * (NPART + 1) * 4;
    __hip_bfloat16* part_g = (__hip_bfloat16*)(ws + off);   // 16384*768*2 = 25.2 MB

    prep_trans<<<NBLK, 256, 0, stream>>>(W, Wb, ids, mask, stoks_g, wts_g, poff_g);

    bm25_part<<<B_ROWS * NPART, NT, 0, stream>>>(stoks_g, wts_g, poff_g, Wb, part_g);

    bm25_combine<<<B_ROWS, NT, 0, stream>>>(part_g, out);
}

// Round 20
// 142.814 us; speedup vs baseline: 1.0279x; 1.0279x over previous
//
#include <hip/hip_runtime.h>
#include <hip/hip_bf16.h>
#include <stdint.h>

#define B_ROWS 2048
#define SEQ 512
#define VOC 30000
#define DMODEL 768
#define K1 1.2f
#define BPAR 0.75f
#define NT 192    // gather: 3 waves; each thread owns one ushort4 (4 bf16) chunk
#define PF 8      // prefetch depth — proven operating point (7x)
#define TGX 235   // ceil(VOC/128) transpose tiles in t
#define TGY 12    // DMODEL/64 transpose tiles in j

// ---------------- Kernel 1: fused doc-prep + W-transpose (R15-proven, 142.9 us total) --
// Blocks [0, B_ROWS): per-doc compact + bitonic sort + BM25 weights; tokens
//   premultiplied by DMODEL/4 (ushort4-row offset).
// Blocks [B_ROWS, ...): transpose W [768][30000] f32 -> Wb [30000][768] bf16
//   (64j x 128t tiles; float2 512B reads, full-128B-line writes, stride-130 LDS).
__launch_bounds__(256)
__global__ void prep_trans(const float* __restrict__ W, __hip_bfloat16* __restrict__ Wb,
                           const int* __restrict__ ids, const int* __restrict__ mask,
                           int* __restrict__ stoks_g, float* __restrict__ wts_g,
                           int* __restrict__ n_g) {
    __shared__ ushort smem[64 * 130];   // 16,640 B
    int bid = blockIdx.x;
    int tid = threadIdx.x;

    if (bid < B_ROWS) {
        // ---- doc-prep role ----
        int b = bid;
        int*   stoks = (int*)smem;                    // 512 ints  (2048 B)
        float* wts   = (float*)((char*)smem + 2048);  // 512 f32   (2048 B)
        int*   nvp   = (int*)((char*)smem + 4096);

        if (tid == 0) *nvp = 0;
        __syncthreads();

        for (int i = tid; i < SEQ; i += 256) {
            int id = ids[(size_t)b * SEQ + i];
            int m  = mask[(size_t)b * SEQ + i];
            if (m == 1 && id > 100 && id < VOC) {
                stoks[atomicAdd(nvp, 1)] = id;
            }
        }
        __syncthreads();
        int n = *nvp;   // == doc_len (positions with multiplicity)

        for (int i = n + tid; i < SEQ; i += 256) stoks[i] = 0x7fffffff;

        for (int k = 2; k <= SEQ; k <<= 1) {
            for (int j = k >> 1; j > 0; j >>= 1) {
                __syncthreads();
                for (int i = tid; i < SEQ; i += 256) {
                    int ixj = i ^ j;
                    if (ixj > i) {
                        int a = stoks[i], c = stoks[ixj];
                        if ((a > c) == ((i & k) == 0)) { stoks[i] = c; stoks[ixj] = a; }
                    }
                }
            }
        }
        __syncthreads();

        float kln = K1 * fmaxf(1.0f + BPAR * ((float)n / 100.0f - 1.0f), 0.5f);
        for (int i = tid; i < n; i += 256) {
            int t = stoks[i];
            int lo = i; while (lo > 0 && stoks[lo - 1] == t) lo--;
            int hi = i; while (hi < n - 1 && stoks[hi + 1] == t) hi++;
            wts[i] = (K1 + 1.0f) / ((float)(hi - lo + 1) + kln);
        }
        __syncthreads();

        for (int i = tid; i < n; i += 256) {
            stoks_g[(size_t)b * SEQ + i] = stoks[i] * (DMODEL / 4);  // ushort4-row offset
            wts_g[(size_t)b * SEQ + i]   = wts[i];
        }
        if (tid == 0) n_g[b] = n;
    } else {
        // ---- transpose role ----
        ushort (*tile)[130] = (ushort(*)[130])smem;   // [j_local][t_local]
        int tb = bid - B_ROWS;
        int bx = tb % TGX, by = tb / TGX;
        int tBase = bx * 128;
        int jBase = by * 64;
        int tx = tid & 63;    // lane
        int ty = tid >> 6;    // wave

#pragma unroll
        for (int jj = 0; jj < 16; jj++) {
            int j = jBase + jj * 4 + ty;
            int t = tBase + tx * 2;
            if (t < VOC) {   // VOC even -> full float2 in range
                float2 v = *(const float2*)(W + (size_t)j * VOC + t);
                ushort2 u;
                u.x = __bfloat16_as_ushort(__float2bfloat16(v.x));
                u.y = __bfloat16_as_ushort(__float2bfloat16(v.y));
                *(ushort2*)&tile[jj * 4 + ty][tx * 2] = u;
            }
        }
        __syncthreads();

#pragma unroll
        for (int i = 0; i < 32; i++) {
            int trow = i * 4 + ty;
            int t = tBase + trow;
            if (t < VOC) {
                ((ushort*)Wb)[(size_t)t * DMODEL + jBase + tx] = tile[tx][trow];
            }
        }
    }
}

__device__ __forceinline__ float b2f(unsigned short h) {
    union { uint32_t u; float f; } v; v.u = ((uint32_t)h) << 16; return v.f;
}

// ---------------- Kernel 2: pure gather + normalize ------------------------------------
// BYTE-IDENTICAL to the 7x-proven gather (106-108 us, FETCH ~326 MB). L1-miss-service
// bound: ~48K 128B-line misses/CU at ~1 line/4-5 cyc ~= the observed duration; HBM/L2/
// VALU/occupancy all have headroom (R19's partitioned variant: FETCH -26%, occupancy
// +50%, duration unchanged).
__launch_bounds__(NT, 6)
__global__ void bm25_gather(const int* __restrict__ stoks_g, const float* __restrict__ wts_g,
                            const int* __restrict__ n_g,
                            const __hip_bfloat16* __restrict__ Wb,
                            float* __restrict__ out) {
    __shared__ int   stoks[SEQ];
    __shared__ float wts[SEQ];
    __shared__ float wred[3];

    int b = blockIdx.x;
    int tid = threadIdx.x;
    int n = n_g[b];   // block-uniform

    for (int i = tid; i < n; i += NT) {
        stoks[i] = stoks_g[(size_t)b * SEQ + i];
        wts[i]   = wts_g[(size_t)b * SEQ + i];
    }
    __syncthreads();

    // gather-accumulate in ascending vocab order; thread owns bf16x4 chunk `tid`
    const ushort4* __restrict__ Wb4 = (const ushort4*)Wb;
    float4 acc = make_float4(0.f, 0.f, 0.f, 0.f);
    int p = 0;
    for (; p + PF <= n; p += PF) {
        ushort4 r[PF];
        float   w[PF];
#pragma unroll
        for (int q = 0; q < PF; q++) {
            r[q] = Wb4[(size_t)stoks[p + q] + tid];
            w[q] = wts[p + q];
        }
#pragma unroll
        for (int q = 0; q < PF; q++) {
            acc.x = fmaf(w[q], b2f(r[q].x), acc.x);
            acc.y = fmaf(w[q], b2f(r[q].y), acc.y);
            acc.z = fmaf(w[q], b2f(r[q].z), acc.z);
            acc.w = fmaf(w[q], b2f(r[q].w), acc.w);
        }
    }
    for (; p < n; p++) {
        float w = wts[p];
        ushort4 r = Wb4[(size_t)stoks[p] + tid];
        acc.x = fmaf(w, b2f(r.x), acc.x);
        acc.y = fmaf(w, b2f(r.y), acc.y);
        acc.z = fmaf(w, b2f(r.z), acc.z);
        acc.w = fmaf(w, b2f(r.w), acc.w);
    }

    // L2 norm over 768 dims (intermediate normalize cancels; 1e-10 term ~1e-10 rel)
    float ss = acc.x * acc.x + acc.y * acc.y + acc.z * acc.z + acc.w * acc.w;
#pragma unroll
    for (int off = 32; off > 0; off >>= 1) ss += __shfl_down(ss, off);
    if ((tid & 63) == 0) wred[tid >> 6] = ss;
    __syncthreads();
    float inv = rsqrtf(fmaxf(wred[0] + wred[1] + wred[2], 1e-30f));

    float4 o;
    o.x = acc.x * inv; o.y = acc.y * inv; o.z = acc.z * inv; o.w = acc.w * inv;
    ((float4*)(out + (size_t)b * DMODEL))[tid] = o;
}

extern "C" void kernel_launch(void* const* d_in, const int* in_sizes, int n_in,
                              void* d_out, int out_size, void* d_ws, size_t ws_size,
                              hipStream_t stream) {
    const int*   ids  = (const int*)d_in[0];
    const int*   mask = (const int*)d_in[1];
    const float* W    = (const float*)d_in[2];
    float* out = (float*)d_out;

    char* ws = (char*)d_ws;
    __hip_bfloat16* Wb = (__hip_bfloat16*)ws;               // 46,080,000 B
    size_t off = (size_t)VOC * DMODEL * sizeof(__hip_bfloat16);
    int*   stoks_g = (int*)(ws + off);        off += (size_t)B_ROWS * SEQ * 4;  // 4 MB
    float* wts_g   = (float*)(ws + off);      off += (size_t)B_ROWS * SEQ * 4;  // 4 MB
    int*   n_g     = (int*)(ws + off);

    prep_trans<<<B_ROWS + TGX * TGY, 256, 0, stream>>>(W, Wb, ids, mask,
                                                       stoks_g, wts_g, n_g);

    bm25_gather<<<B_ROWS, NT, 0, stream>>>(stoks_g, wts_g, n_g, Wb, out);
}